// Round 1
// baseline (96.134 us; speedup 1.0000x reference)
//
#include <hip/hip_runtime.h>
#include <math.h>

#define NB 8
#define NN 2048
#define ND 128
#define NHID 256
#define PROJ 64
#define TH_IN 387
#define TH_HID 128

// ---------------- Kernel A: seed/argmax, kq = Wk^T (Wq @ x_seed), theta MLP ----
__global__ __launch_bounds__(256) void seed_theta_kernel(
    const float* __restrict__ x, const float* __restrict__ seed_ctx,
    const float* __restrict__ local_stats, const float* __restrict__ cmask,
    const float* __restrict__ Wq, const float* __restrict__ Wk,
    const float* __restrict__ W1, const float* __restrict__ b1,
    const float* __restrict__ W2, const float* __restrict__ b2,
    float* __restrict__ kq_ws, float* __restrict__ theta_ws,
    float* __restrict__ out_theta)
{
  const int b = blockIdx.x;
  const int t = threadIdx.x;
  __shared__ float sv[256]; __shared__ int si[256];
  __shared__ float sx[ND];
  __shared__ float sq[PROJ];
  __shared__ float tin[TH_IN];
  __shared__ float sred[TH_HID];

  // argmax(cluster_mask[b]) -> first index attaining max (jnp.argmax semantics)
  float bv = -1e30f; int bi = 0x7fffffff;
  for (int n = t; n < NN; n += 256) {
    float v = cmask[b*NN + n];
    if (v > bv || (v == bv && n < bi)) { bv = v; bi = n; }
  }
  sv[t] = bv; si[t] = bi;
  __syncthreads();
  for (int s = 128; s > 0; s >>= 1) {
    if (t < s) {
      float v2 = sv[t+s]; int i2 = si[t+s];
      if (v2 > sv[t] || (v2 == sv[t] && i2 < si[t])) { sv[t] = v2; si[t] = i2; }
    }
    __syncthreads();
  }
  const int seed = si[0];

  if (t < ND) sx[t] = x[((size_t)b*NN + seed)*ND + t];
  __syncthreads();

  // q[h] = sum_d Wq[h,d]*sx[d]
  if (t < PROJ) {
    float acc = 0.f;
    for (int d = 0; d < ND; ++d) acc += Wq[t*ND + d] * sx[d];
    sq[t] = acc;
  }
  __syncthreads();

  // kq[d] = sum_h Wk[h,d]*q[h]
  if (t < ND) {
    float acc = 0.f;
    for (int h = 0; h < PROJ; ++h) acc += Wk[h*ND + t] * sq[h];
    kq_ws[b*ND + t] = acc;
  }

  // theta head
  for (int i = t; i < ND + NHID; i += 256) tin[i] = seed_ctx[b*(ND+NHID) + i];
  if (t < 3) tin[ND + NHID + t] = local_stats[b*3 + t];
  __syncthreads();
  if (t < TH_HID) {
    float acc = b1[t];
    for (int i = 0; i < TH_IN; ++i) acc += tin[i] * W1[i*TH_HID + t];
    acc = fmaxf(acc, 0.f);          // ReLU
    sred[t] = acc * W2[t];
  }
  __syncthreads();
  for (int s = 64; s > 0; s >>= 1) {
    if (t < s && t + s < TH_HID) sred[t] += sred[t+s];
    __syncthreads();
  }
  if (t == 0) {
    float th = sred[0] + b2[0];
    theta_ws[b] = th;
    out_theta[b] = th;
  }
}

// ---------------- Kernel B: one wave per adj row -----------------------------
__global__ __launch_bounds__(256) void row_kernel(
    const float* __restrict__ x, const float* __restrict__ adj,
    const float* __restrict__ cmask, const float* __restrict__ candm,
    const float* __restrict__ kq_ws, const float* __restrict__ theta_ws,
    float* __restrict__ out_hard, float* __restrict__ out_p)
{
  const int t = threadIdx.x;
  const int wave = t >> 6, lane = t & 63;
  const int row0 = blockIdx.x * 4;
  const int b = row0 >> 11;               // 2048 rows per batch, 4 rows/block
  __shared__ float sCm[NN];
  __shared__ float sKq[ND];
  __shared__ float sTheta;

  const float4* cm4 = (const float4*)(cmask + b*NN);
  float4* sCm4 = (float4*)sCm;
  for (int i = t; i < NN/4; i += 256) sCm4[i] = cm4[i];
  if (t < ND) sKq[t] = kq_ws[b*ND + t];
  if (t == 0) sTheta = theta_ws[b];
  __syncthreads();

  const int row = row0 + wave;            // == b*NN + n
  const int n = row & (NN - 1);
  const float4* a4 = (const float4*)(adj + (size_t)row * NN);
  float deg = 0.f, e2c = 0.f;
  #pragma unroll
  for (int k = 0; k < 8; ++k) {
    const int idx = k*64 + lane;
    float4 a = a4[idx];
    float4 c = sCm4[idx];
    deg += a.x + a.y + a.z + a.w;
    e2c += a.x*c.x + a.y*c.y + a.z*c.z + a.w*c.w;
  }
  const float2* x2 = (const float2*)(x + ((size_t)row)*ND);
  float2 xv = x2[lane];
  float sc = xv.x * sKq[2*lane] + xv.y * sKq[2*lane + 1];

  for (int off = 32; off; off >>= 1) {
    deg += __shfl_xor(deg, off);
    e2c += __shfl_xor(e2c, off);
    sc  += __shfl_xor(sc, off);
  }

  if (lane == 0) {
    float dd = fmaxf(deg, 1.0f);
    float cand = sc * 0.125f + 0.2f * (e2c / dd);   // /sqrt(64) == *0.125 exact
    float logit = cand - sTheta;                    // TAU == 1
    float p = 1.0f / (1.0f + expf(-logit));
    p *= candm[row];
    out_p[row] = p;
    out_hard[row] = (p > 0.5f) ? 1.0f : 0.0f;
  }
}

// ---------------- Kernel C: per-batch count + stable top-2 + trim ------------
__global__ __launch_bounds__(256) void trim_kernel(
    float* __restrict__ out_hard, float* __restrict__ out_p)
{
  const int b = blockIdx.x;
  const int t = threadIdx.x;
  float* p = out_p + b*NN;
  float* hard = out_hard + b*NN;
  __shared__ int scount[256];
  __shared__ float sv1[256]; __shared__ int si1[256];
  __shared__ float sv2[256]; __shared__ int si2[256];
  __shared__ int s_trim, s_k1, s_k2;

  int cnt = 0;
  float v1 = -1e30f, v2 = -1e30f; int i1 = 0, i2 = 0;
  const int base = t*8;                 // contiguous chunk: thread order == index order
  for (int j = 0; j < 8; ++j) {
    const int nidx = base + j;
    const float v = p[nidx];
    if (v > 0.5f) ++cnt;
    if (v > v1)      { v2 = v1; i2 = i1; v1 = v; i1 = nidx; }
    else if (v > v2) { v2 = v;  i2 = nidx; }
  }
  scount[t] = cnt; sv1[t]=v1; si1[t]=i1; sv2[t]=v2; si2[t]=i2;
  __syncthreads();
  for (int s = 128; s > 0; s >>= 1) {
    if (t < s) scount[t] += scount[t+s];
    __syncthreads();
  }
  if (t == 0) {
    // sequential merge in index order; strict '>' keeps earliest index on ties
    float V1=-1e30f, V2=-1e30f; int I1=0, I2=0;
    for (int u = 0; u < 256; ++u) {
      float a = sv1[u]; int ia = si1[u];
      if (a > V1)      { V2=V1; I2=I1; V1=a; I1=ia; }
      else if (a > V2) { V2=a;  I2=ia; }
      float c = sv2[u]; int ic = si2[u];
      if (c > V1)      { V2=V1; I2=I1; V1=c; I1=ic; }
      else if (c > V2) { V2=c;  I2=ic; }
    }
    s_trim = (scount[0] > 2) ? 1 : 0;   // over = count - (CLUSTER_SIZE_MAX-1) > 0
    s_k1 = I1; s_k2 = I2;
  }
  __syncthreads();
  if (s_trim) {
    for (int nidx = t; nidx < NN; nidx += 256) {
      if (nidx != s_k1 && nidx != s_k2) { p[nidx] = 0.f; hard[nidx] = 0.f; }
    }
  }
}

extern "C" void kernel_launch(void* const* d_in, const int* in_sizes, int n_in,
                              void* d_out, int out_size, void* d_ws, size_t ws_size,
                              hipStream_t stream) {
  const float* x          = (const float*)d_in[0];
  const float* adj        = (const float*)d_in[1];
  const float* seed_ctx   = (const float*)d_in[2];
  const float* local_st   = (const float*)d_in[3];
  const float* cmask      = (const float*)d_in[4];
  const float* candm      = (const float*)d_in[5];
  const float* Wq         = (const float*)d_in[6];
  const float* Wk         = (const float*)d_in[7];
  const float* W1         = (const float*)d_in[8];
  const float* b1         = (const float*)d_in[9];
  const float* W2         = (const float*)d_in[10];
  const float* b2         = (const float*)d_in[11];

  float* out      = (float*)d_out;
  float* out_hard = out;                // [B,N]
  float* out_p    = out + NB*NN;        // [B,N]
  float* out_th   = out + 2*NB*NN;      // [B]

  float* ws       = (float*)d_ws;
  float* kq_ws    = ws;                 // B*D floats
  float* theta_ws = ws + NB*ND;         // B floats

  seed_theta_kernel<<<NB, 256, 0, stream>>>(x, seed_ctx, local_st, cmask,
                                            Wq, Wk, W1, b1, W2, b2,
                                            kq_ws, theta_ws, out_th);
  row_kernel<<<(NB*NN)/4, 256, 0, stream>>>(x, adj, cmask, candm,
                                            kq_ws, theta_ws, out_hard, out_p);
  trim_kernel<<<NB, 256, 0, stream>>>(out_hard, out_p);
}

// Round 2
// 54.532 us; speedup vs baseline: 1.7629x; 1.7629x over previous
//
#include <hip/hip_runtime.h>
#include <math.h>

#define NB 8
#define NN 2048
#define ND 128
#define NHID 256
#define PROJ 64
#define TH_IN 387
#define TH_HID 128

// ---------------- Kernel A: seed/argmax, kq = Wk^T (Wq @ x_seed), theta MLP ----
// 1024 threads (16 waves) per block, one block per batch. All phases spread
// across >=8 waves so L2-latency is hidden by TLP, not serial accumulation.
__global__ __launch_bounds__(1024) void seed_theta_kernel(
    const float* __restrict__ x, const float* __restrict__ seed_ctx,
    const float* __restrict__ local_stats, const float* __restrict__ cmask,
    const float* __restrict__ Wq, const float* __restrict__ Wk,
    const float* __restrict__ W1, const float* __restrict__ b1,
    const float* __restrict__ W2, const float* __restrict__ b2,
    float* __restrict__ kq_ws, float* __restrict__ theta_ws,
    float* __restrict__ out_theta)
{
  const int b = blockIdx.x;
  const int t = threadIdx.x;
  const int wave = t >> 6, lane = t & 63;

  __shared__ float sv[1024]; __shared__ int si[1024];
  __shared__ float sx[ND];
  __shared__ float sq[PROJ];
  __shared__ float tin[TH_IN];
  __shared__ float part[8][TH_HID];
  __shared__ float sred[TH_HID];

  // ---- argmax(cluster_mask[b]): earliest index attaining the max ----
  {
    float v0 = cmask[b*NN + t];
    float v1 = cmask[b*NN + t + 1024];
    float bv = v0; int bi = t;
    if (v1 > bv) { bv = v1; bi = t + 1024; }
    sv[t] = bv; si[t] = bi;
  }
  __syncthreads();
  for (int s = 512; s > 0; s >>= 1) {
    if (t < s) {
      float v2 = sv[t+s]; int i2 = si[t+s];
      if (v2 > sv[t] || (v2 == sv[t] && i2 < si[t])) { sv[t] = v2; si[t] = i2; }
    }
    __syncthreads();
  }
  const int seed = si[0];

  if (t < ND) sx[t] = x[((size_t)b*NN + seed)*ND + t];
  __syncthreads();

  // ---- q[h] = Wq[h,:] . sx  — one h per (wave, j), lane-split + shfl reduce
  {
    const int h = wave*4;
    #pragma unroll
    for (int j = 0; j < 4; ++j) {
      float a = Wq[(h+j)*ND + lane] * sx[lane]
              + Wq[(h+j)*ND + 64 + lane] * sx[64 + lane];
      for (int off = 32; off; off >>= 1) a += __shfl_xor(a, off);
      if (lane == 0) sq[h+j] = a;
    }
  }
  __syncthreads();

  // ---- kq[d] = sum_h Wk[h,d]*q[h] — split h into 8 chunks across threads
  {
    const int c = t >> 7;            // 0..7
    const int d = t & 127;
    float acc = 0.f;
    #pragma unroll
    for (int j = 0; j < 8; ++j) acc += Wk[(c*8 + j)*ND + d] * sq[c*8 + j];
    part[c][d] = acc;
  }
  __syncthreads();
  if (t < ND) {
    float acc = 0.f;
    #pragma unroll
    for (int c = 0; c < 8; ++c) acc += part[c][t];
    kq_ws[b*ND + t] = acc;
  }

  // ---- theta head: h = Linear(387->128) -> ReLU -> Linear(128->1)
  if (t < ND + NHID) tin[t] = seed_ctx[b*(ND+NHID) + t];
  if (t >= ND + NHID && t < TH_IN) tin[t] = local_stats[b*3 + (t - (ND+NHID))];
  __syncthreads();
  {
    const int c = t >> 7;            // i-chunk 0..7, ~49 each
    const int h = t & 127;
    const int i0 = c*49;
    const int i1 = (c == 7) ? TH_IN : i0 + 49;
    float acc = 0.f;
    for (int i = i0; i < i1; ++i) acc += tin[i] * W1[i*TH_HID + h];
    part[c][h] = acc;
  }
  __syncthreads();
  if (t < TH_HID) {
    float acc = b1[t];
    #pragma unroll
    for (int c = 0; c < 8; ++c) acc += part[c][t];
    acc = fmaxf(acc, 0.f);
    sred[t] = acc * W2[t];
  }
  __syncthreads();
  if (t < 64) {
    float v = sred[t] + sred[t + 64];
    for (int off = 32; off; off >>= 1) v += __shfl_xor(v, off);
    if (t == 0) {
      float th = v + b2[0];
      theta_ws[b] = th;
      out_theta[b] = th;
    }
  }
}

// ---------------- Kernel B: one wave per adj row (HBM-roofline stream) -------
__global__ __launch_bounds__(256) void row_kernel(
    const float* __restrict__ x, const float* __restrict__ adj,
    const float* __restrict__ cmask, const float* __restrict__ candm,
    const float* __restrict__ kq_ws, const float* __restrict__ theta_ws,
    float* __restrict__ out_hard, float* __restrict__ out_p)
{
  const int t = threadIdx.x;
  const int wave = t >> 6, lane = t & 63;
  const int row0 = blockIdx.x * 4;
  const int b = row0 >> 11;               // 2048 rows per batch, 4 rows/block
  __shared__ float sCm[NN];
  __shared__ float sKq[ND];
  __shared__ float sTheta;

  const float4* cm4 = (const float4*)(cmask + b*NN);
  float4* sCm4 = (float4*)sCm;
  for (int i = t; i < NN/4; i += 256) sCm4[i] = cm4[i];
  if (t < ND) sKq[t] = kq_ws[b*ND + t];
  if (t == 0) sTheta = theta_ws[b];
  __syncthreads();

  const int row = row0 + wave;            // == b*NN + n
  const float4* a4 = (const float4*)(adj + (size_t)row * NN);
  float deg = 0.f, e2c = 0.f;
  #pragma unroll
  for (int k = 0; k < 8; ++k) {
    const int idx = k*64 + lane;
    float4 a = a4[idx];
    float4 c = sCm4[idx];
    deg += a.x + a.y + a.z + a.w;
    e2c += a.x*c.x + a.y*c.y + a.z*c.z + a.w*c.w;
  }
  const float2* x2 = (const float2*)(x + ((size_t)row)*ND);
  float2 xv = x2[lane];
  float sc = xv.x * sKq[2*lane] + xv.y * sKq[2*lane + 1];

  for (int off = 32; off; off >>= 1) {
    deg += __shfl_xor(deg, off);
    e2c += __shfl_xor(e2c, off);
    sc  += __shfl_xor(sc, off);
  }

  if (lane == 0) {
    float dd = fmaxf(deg, 1.0f);
    float cand = sc * 0.125f + 0.2f * (e2c / dd);   // /sqrt(64) == *0.125 exact
    float logit = cand - sTheta;                    // TAU == 1
    float p = 1.0f / (1.0f + expf(-logit));
    p *= candm[row];
    out_p[row] = p;
    out_hard[row] = (p > 0.5f) ? 1.0f : 0.0f;
  }
}

// ---------------- Kernel C: per-batch count + stable top-2 + trim ------------
__global__ __launch_bounds__(256) void trim_kernel(
    float* __restrict__ out_hard, float* __restrict__ out_p)
{
  const int b = blockIdx.x;
  const int t = threadIdx.x;
  float* p = out_p + b*NN;
  float* hard = out_hard + b*NN;
  __shared__ int scnt[256];
  __shared__ float sv1[256]; __shared__ int si1[256];
  __shared__ float sv2[256]; __shared__ int si2[256];
  __shared__ int s_trim, s_k1, s_k2;

  int cnt = 0;
  float v1 = -1e30f, v2 = -1e30f; int i1 = 0, i2 = 0;
  const int base = t*8;                 // contiguous chunk: thread order == index order
  #pragma unroll
  for (int j = 0; j < 8; ++j) {
    const int nidx = base + j;
    const float v = p[nidx];
    if (v > 0.5f) ++cnt;
    if (v > v1)      { v2 = v1; i2 = i1; v1 = v; i1 = nidx; }
    else if (v > v2) { v2 = v;  i2 = nidx; }
  }
  scnt[t] = cnt; sv1[t]=v1; si1[t]=i1; sv2[t]=v2; si2[t]=i2;
  __syncthreads();
  // tree-merge: t's set covers strictly lower indices than t+s's set, so on
  // value ties keeping t's entry preserves lax.top_k's lowest-index tie-break.
  for (int s = 128; s > 0; s >>= 1) {
    if (t < s) {
      scnt[t] += scnt[t+s];
      float B1 = sv1[t+s]; int Bi1 = si1[t+s];
      float B2 = sv2[t+s]; int Bi2 = si2[t+s];
      float V1 = sv1[t], V2 = sv2[t]; int I1 = si1[t], I2 = si2[t];
      if (B1 > V1)      { V2=V1; I2=I1; V1=B1; I1=Bi1; }
      else if (B1 > V2) { V2=B1; I2=Bi1; }
      if (B2 > V1)      { V2=V1; I2=I1; V1=B2; I1=Bi2; }
      else if (B2 > V2) { V2=B2; I2=Bi2; }
      sv1[t]=V1; si1[t]=I1; sv2[t]=V2; si2[t]=I2;
    }
    __syncthreads();
  }
  if (t == 0) {
    s_trim = (scnt[0] > 2) ? 1 : 0;     // over = count - (CLUSTER_SIZE_MAX-1) > 0
    s_k1 = si1[0]; s_k2 = si2[0];
  }
  __syncthreads();
  if (s_trim) {
    for (int nidx = t; nidx < NN; nidx += 256) {
      if (nidx != s_k1 && nidx != s_k2) { p[nidx] = 0.f; hard[nidx] = 0.f; }
    }
  }
}

extern "C" void kernel_launch(void* const* d_in, const int* in_sizes, int n_in,
                              void* d_out, int out_size, void* d_ws, size_t ws_size,
                              hipStream_t stream) {
  const float* x          = (const float*)d_in[0];
  const float* adj        = (const float*)d_in[1];
  const float* seed_ctx   = (const float*)d_in[2];
  const float* local_st   = (const float*)d_in[3];
  const float* cmask      = (const float*)d_in[4];
  const float* candm      = (const float*)d_in[5];
  const float* Wq         = (const float*)d_in[6];
  const float* Wk         = (const float*)d_in[7];
  const float* W1         = (const float*)d_in[8];
  const float* b1         = (const float*)d_in[9];
  const float* W2         = (const float*)d_in[10];
  const float* b2         = (const float*)d_in[11];

  float* out      = (float*)d_out;
  float* out_hard = out;                // [B,N]
  float* out_p    = out + NB*NN;        // [B,N]
  float* out_th   = out + 2*NB*NN;      // [B]

  float* ws       = (float*)d_ws;
  float* kq_ws    = ws;                 // B*D floats
  float* theta_ws = ws + NB*ND;         // B floats

  seed_theta_kernel<<<NB, 1024, 0, stream>>>(x, seed_ctx, local_st, cmask,
                                             Wq, Wk, W1, b1, W2, b2,
                                             kq_ws, theta_ws, out_th);
  row_kernel<<<(NB*NN)/4, 256, 0, stream>>>(x, adj, cmask, candm,
                                            kq_ws, theta_ws, out_hard, out_p);
  trim_kernel<<<NB, 256, 0, stream>>>(out_hard, out_p);
}